// Round 4
// baseline (270.539 us; speedup 1.0000x reference)
//
#include <hip/hip_runtime.h>

// inputs  [B=64, H=512, W=512, C=3] f32 ; offsets [64,2] f32
// output  [B=64, 64, 64, C*DEPTH=9] f32, channel index = c*DEPTH + d
#define OSZ 64
#define NB  64
#define IH  512
#define IW  512
#define NC  3
#define ND  3

// LDS worst case: d=2 -> 3 planes * 19 rows * 268 pitch floats = 61.1 KB
#define LDS_FLOATS (3 * 19 * 268)

// bank swizzle: insert one pad word every 32 -> stride-K reads are <=2-way
__device__ __forceinline__ int swz(int p) { return p + (p >> 5); }

// k x k mean of unit-spaced bilinear samples == separable (K+1)-tap filter
// with per-axis weights [1-f, 1, ..., 1, f] / K; OOB taps get weight 0.
// Region staged in LDS (clamped addresses; zero-weighting handles OOB).
template<int K, int R>
__device__ __forceinline__ void glimpse_tile(const float* __restrict__ img,
                                             float* __restrict__ out,
                                             float* __restrict__ lds,
                                             int b, int tile, int d,
                                             float cy, float cx) {
    constexpr int ROWS  = R * K + 3;            // +1 margin both sides (fp jitter)
    constexpr int COLS  = OSZ * K + 3;          // pixels
    constexpr int PITCH = COLS + (COLS >> 5) + 1;
    constexpr int PLANE = ROWS * PITCH;
    const float halfspan = (float)(OSZ * K - 1) * 0.5f;
    const int tid = threadIdx.x;
    const int yfirst = tile * R;

    // region origin: same fp expression as per-output coords (exact match at
    // the first output), minus 1 margin
    float yb0 = cy + ((float)(yfirst * K) - halfspan);
    float xb0 = cx + (0.0f - halfspan);
    int ry0 = (int)floorf(yb0) - 1;
    int rx0 = (int)floorf(xb0) - 1;

    // ---- fill LDS: coalesced 12B/lane reads, clamped at image edges ----
    for (int lin = tid; lin < ROWS * COLS; lin += 256) {
        int r = lin / COLS;            // COLS is constexpr -> magic-mul
        int p = lin - r * COLS;
        int gy = ry0 + r; gy = gy < 0 ? 0 : (gy > IH - 1 ? IH - 1 : gy);
        int gx = rx0 + p; gx = gx < 0 ? 0 : (gx > IW - 1 ? IW - 1 : gx);
        const float* src = img + (((size_t)b * IH + gy) * IW + gx) * NC;
        int a = r * PITCH + swz(p);
        lds[a]             = src[0];
        lds[PLANE + a]     = src[1];
        lds[2 * PLANE + a] = src[2];
    }
    __syncthreads();

    // ---- compute from LDS ----
    int x = tid & 63;
    float xbase = cx + ((float)(x * K) - halfspan);   // identical fp to reference
    float x0f = floorf(xbase);
    float fx = xbase - x0f;
    int x0 = (int)x0f;
    int ix = x0 - rx0;                                // in [0, COLS-1-K]

    float wx[K + 1];
    wx[0] = 1.0f - fx;
#pragma unroll
    for (int s = 1; s < K; ++s) wx[s] = 1.0f;
    wx[K] = fx;
#pragma unroll
    for (int s = 0; s <= K; ++s) {
        int xi = x0 + s;
        if (xi < 0 || xi >= IW) wx[s] = 0.0f;
    }

    const float inv = 1.0f / (float)(K * K);
#pragma unroll
    for (int j = 0; j < R / 4; ++j) {
        int y = yfirst + (tid >> 6) + j * 4;
        float ybase = cy + ((float)(y * K) - halfspan);
        float y0f = floorf(ybase);
        float fy = ybase - y0f;
        int y0 = (int)y0f;
        int iy = y0 - ry0;                            // in [0, ROWS-1-K]

        float a0 = 0.f, a1 = 0.f, a2 = 0.f;
#pragma unroll
        for (int r = 0; r <= K; ++r) {
            int yi = y0 + r;
            float wy = (r == 0) ? (1.0f - fy) : ((r == K) ? fy : 1.0f);
            if (yi < 0 || yi >= IH) continue;         // zero-weight row
            const float* p0 = lds + (iy + r) * PITCH;
            float r0 = 0.f, r1 = 0.f, r2 = 0.f;
#pragma unroll
            for (int s = 0; s <= K; ++s) {
                float w = wx[s];
                int a = swz(ix + s);
                r0 += w * p0[a];
                r1 += w * p0[PLANE + a];
                r2 += w * p0[2 * PLANE + a];
            }
            a0 += wy * r0; a1 += wy * r1; a2 += wy * r2;
        }
        size_t o = (((size_t)b * OSZ + y) * OSZ + x) * (NC * ND) + d;
        out[o]          = a0 * inv;
        out[o + ND]     = a1 * inv;
        out[o + 2 * ND] = a2 * inv;
    }
}

__global__ __launch_bounds__(256)
void SpatialGlimpse_kernel(const float* __restrict__ img,
                           const float* __restrict__ off,
                           float* __restrict__ out) {
    __shared__ float lds[LDS_FLOATS];
    int bid = blockIdx.x;
    // blocks: [0,64) d0 (1 tile/b) | [64,320) d1 (4 tiles/b) | [320,1344) d2 (16 tiles/b)
    int d, b, tile;
    if (bid < NB)               { d = 0; b = bid;            tile = 0; }
    else if (bid < NB + NB * 4) { int t = bid - NB;     d = 1; b = t >> 2; tile = t & 3; }
    else                        { int t = bid - NB * 5; d = 2; b = t >> 4; tile = t & 15; }

    float cy = (off[2 * b + 0] + 1.0f) * ((float)IH * 0.5f);
    float cx = (off[2 * b + 1] + 1.0f) * ((float)IW * 0.5f);

    if (d == 0)      glimpse_tile<1, 64>(img, out, lds, b, tile, 0, cy, cx);
    else if (d == 1) glimpse_tile<2, 16>(img, out, lds, b, tile, 1, cy, cx);
    else             glimpse_tile<4, 4>(img, out, lds, b, tile, 2, cy, cx);
}

extern "C" void kernel_launch(void* const* d_in, const int* in_sizes, int n_in,
                              void* d_out, int out_size, void* d_ws, size_t ws_size,
                              hipStream_t stream) {
    const float* img = (const float*)d_in[0];
    const float* off = (const float*)d_in[1];
    float* out = (float*)d_out;

    const int grid = NB + NB * 4 + NB * 16;   // 1344 blocks, 256 threads
    SpatialGlimpse_kernel<<<grid, 256, 0, stream>>>(img, off, out);
}

// Round 10
// 246.212 us; speedup vs baseline: 1.0988x; 1.0988x over previous
//
#include <hip/hip_runtime.h>

// inputs  [B=64, H=512, W=512, C=3] f32 ; offsets [64,2] f32
// output  [B=64, 64, 64, C*DEPTH=9] f32, channel index = c*DEPTH + d
#define OSZ 64
#define NB  64
#define IH  512
#define IW  512
#define NC  3
#define ND  3

// k x k mean of unit-spaced bilinear samples == separable (K+1)-tap filter
// with per-axis weights [1-f, 1, ..., 1, f] / K; OOB taps get weight 0
// (identical math to the round-1 kernel that passed absmax=0.0078).
template<int K>
__device__ __forceinline__ void glimpse_eval(const float* __restrict__ img,
                                             int b, int y, int x,
                                             float cy, float cx,
                                             float* __restrict__ out3) {
    const float halfspan = (float)(OSZ * K - 1) * 0.5f;
    float ybase = cy + ((float)(y * K) - halfspan);   // exact: single rounding
    float xbase = cx + ((float)(x * K) - halfspan);
    float y0f = floorf(ybase), x0f = floorf(xbase);
    float fy = ybase - y0f, fx = xbase - x0f;
    int y0 = (int)y0f, x0 = (int)x0f;

    float wx[K + 1];
    wx[0] = 1.0f - fx;
#pragma unroll
    for (int s = 1; s < K; ++s) wx[s] = 1.0f;
    wx[K] = fx;
#pragma unroll
    for (int s = 0; s <= K; ++s) {
        int xi = x0 + s;
        if (xi < 0 || xi >= IW) wx[s] = 0.0f;
    }

    float a0 = 0.f, a1 = 0.f, a2 = 0.f;
#pragma unroll
    for (int r = 0; r <= K; ++r) {
        int yi = y0 + r;
        float wy = (r == 0) ? (1.0f - fy) : ((r == K) ? fy : 1.0f);
        if (yi < 0 || yi >= IH) continue;  // zero-weight row: skip entirely
        const float* rowp = img + ((size_t)b * IH + (size_t)yi) * (IW * NC);
        float r0 = 0.f, r1 = 0.f, r2 = 0.f;
#pragma unroll
        for (int s = 0; s <= K; ++s) {
            int xi = x0 + s;
            int xc = xi < 0 ? 0 : (xi >= IW ? IW - 1 : xi);  // safe addr; w=0 if OOB
            const float* p = rowp + xc * NC;
            float w = wx[s];
            r0 += w * p[0];
            r1 += w * p[1];
            r2 += w * p[2];
        }
        a0 += wy * r0; a1 += wy * r1; a2 += wy * r2;
    }
    const float inv = 1.0f / (float)(K * K);
    out3[0] = a0 * inv; out3[1] = a1 * inv; out3[2] = a2 * inv;
}

// One thread per output pixel (b,y,x); computes all DEPTH scales so the
// d0/d1 taps hit the cache lines just pulled by the d2 5x5 footprint,
// and all 9 output channels store contiguously (36 B/lane).
__global__ __launch_bounds__(256)
void SpatialGlimpse_kernel(const float* __restrict__ img,
                           const float* __restrict__ off,
                           float* __restrict__ out) {
    int idx = blockIdx.x * 256 + threadIdx.x;   // ((b*64+y)*64+x)
    int x = idx & 63;
    int y = (idx >> 6) & 63;
    int b = idx >> 12;

    float cy = (off[2 * b + 0] + 1.0f) * ((float)IH * 0.5f);
    float cx = (off[2 * b + 1] + 1.0f) * ((float)IW * 0.5f);

    float v0[3], v1[3], v2[3];
    glimpse_eval<4>(img, b, y, x, cy, cx, v2);  // widest footprint first:
    glimpse_eval<2>(img, b, y, x, cy, cx, v1);  // d1/d0 taps are L1-resident
    glimpse_eval<1>(img, b, y, x, cy, cx, v0);

    size_t o = (size_t)idx * (NC * ND);
    out[o + 0] = v0[0]; out[o + 1] = v1[0]; out[o + 2] = v2[0];
    out[o + 3] = v0[1]; out[o + 4] = v1[1]; out[o + 5] = v2[1];
    out[o + 6] = v0[2]; out[o + 7] = v1[2]; out[o + 8] = v2[2];
}

extern "C" void kernel_launch(void* const* d_in, const int* in_sizes, int n_in,
                              void* d_out, int out_size, void* d_ws, size_t ws_size,
                              hipStream_t stream) {
    const float* img = (const float*)d_in[0];
    const float* off = (const float*)d_in[1];
    float* out = (float*)d_out;

    const int total = NB * OSZ * OSZ;          // 262144 threads
    const int block = 256;
    const int grid = total / block;            // 1024 blocks
    SpatialGlimpse_kernel<<<grid, block, 0, stream>>>(img, off, out);
}